// Round 19
// baseline (383.658 us; speedup 1.0000x reference)
//
#include <hip/hip_runtime.h>
#include <hip/hip_bf16.h>
#include <math.h>

// Problem constants
#define HH 128
#define WWW 128
#define BB 8
#define MM (HH*WWW*BB)      // 131072 rows (h,w,b)

typedef unsigned int u32;
typedef unsigned short u16;

using frag_ab = __attribute__((ext_vector_type(8))) short;   // 8 bf16
using frag_cd = __attribute__((ext_vector_type(4))) float;   // 4 f32

__device__ __forceinline__ float b2f(u16 s){ return __uint_as_float(((u32)s)<<16); }
__device__ __forceinline__ u16 f2b(float f){
    u32 u = __float_as_uint(f);
    return (u16)((u + 0x7fffu + ((u>>16)&1u)) >> 16);
}
__device__ __forceinline__ u32 pack2(float lo, float hi){
    return (u32)f2b(lo) | ((u32)f2b(hi)<<16);
}

// ---------------- K0: prep: WtB (front W bf16 n-major), WoTn, trig ----------
__global__ __launch_bounds__(128) void k_prep(
    const float* __restrict__ th_f, const float* __restrict__ th_r,
    const float* __restrict__ W_in, const float* __restrict__ W_lam,
    const float* __restrict__ W_gate, const float* __restrict__ W_out,
    float* __restrict__ trig, u16* __restrict__ WoTn, u16* __restrict__ WtB)
{
    int t = blockIdx.x*128 + threadIdx.x;     // 897 blocks x 128
    if (t < 81920) {
        int n = t >> 7, k = t & 127;
        float v = (n < 256) ? W_in[k*256 + n]
                : (n < 384) ? W_lam[k*128 + (n-256)]
                            : W_gate[k*256 + (n-384)];
        WtB[t] = f2b(v);
    } else if (t < 114688) {                  // WoTn[n][k] = W_out[k][n]
        int u = t - 81920;
        int n = u >> 8, k = u & 255;
        WoTn[u] = f2b(W_out[(size_t)k*128 + n]);
    } else if (t < 114816) {
        int d = t - 114688;
        trig[d]     = cosf(th_f[d]); trig[128+d] = sinf(th_f[d]);
        trig[256+d] = cosf(th_r[d]); trig[384+d] = sinf(th_r[d]);
    }
}

// ---------------- K0b: cast x f32 -> bf16 (xb aliases P's ws space) ---------
__global__ __launch_bounds__(256) void k_cast(const float4* __restrict__ x,
                                              uint4* __restrict__ xb){
    size_t i = (size_t)blockIdx.x*256 + threadIdx.x;   // 2,097,152 threads
    float4 a = x[2*i], b = x[2*i+1];
    uint4 o;
    o.x = pack2(a.x, a.y); o.y = pack2(a.z, a.w);
    o.z = pack2(b.x, b.y); o.w = pack2(b.z, b.w);
    xb[i] = o;
}

// ---------------- K1: front GEMM via MFMA; B in LDS, A direct from L2 -------
// Grid 5120 = 1024 m-tiles x 5 nt (m-major). LDS 32 KiB -> 4+ blocks/CU.
__global__ __launch_bounds__(256, 4) void k_front_mfma(
    const u16* __restrict__ xb, const u16* __restrict__ WtB,
    const float* __restrict__ b_in, const float* __restrict__ b_lam,
    const float* __restrict__ b_gate,
    u16* __restrict__ SC, u16* __restrict__ OM, u16* __restrict__ GATE)
{
    __shared__ __align__(16) char Bs[32768];   // 128 n-rows x 256B, XOR-swizzled

    int bid = blockIdx.x;
    int mt = bid / 5, nt = bid % 5;
    int m0 = mt * 128;
    int tid = threadIdx.x;

    #pragma unroll
    for (int it = 0; it < 8; ++it) {           // stage B: raw bf16 copy
        int u = it*256 + tid;
        int row = u >> 4, c16 = u & 15;
        int dst = (row<<8) + ((c16<<4) ^ ((row&7)<<4));
        *(uint4*)(Bs + dst) =
            *(const uint4*)(WtB + (size_t)(nt*128+row)*128 + c16*8);
    }
    __syncthreads();

    int lane = tid & 63, w = tid >> 6;
    int wm = w*32;
    int lr = lane & 15, lk = (lane>>4)*8;
    int rb = (lane>>4)*4;

    // per-lane A row bases (u16 units)
    const u16* a0p = xb + (size_t)(m0 + wm + lr)*128 + lk;
    const u16* a1p = a0p + 16*128;

    frag_cd acc[2][8] = {};
    #pragma unroll
    for (int kt = 0; kt < 4; ++kt) {
        frag_ab a0 = *(const frag_ab*)(a0p + kt*32);
        frag_ab a1 = *(const frag_ab*)(a1p + kt*32);
        int kb2 = (kt*32 + lk)*2;
        #pragma unroll
        for (int nf = 0; nf < 8; ++nf) {
            int rn = nf*16 + lr;
            frag_ab bf = *(const frag_ab*)(Bs + (rn<<8) + (kb2 ^ ((rn&7)<<4)));
            acc[0][nf] = __builtin_amdgcn_mfma_f32_16x16x32_bf16(a0, bf, acc[0][nf], 0,0,0);
            acc[1][nf] = __builtin_amdgcn_mfma_f32_16x16x32_bf16(a1, bf, acc[1][nf], 0,0,0);
        }
    }

    const float* bsrc = (nt < 2) ? b_in + nt*128
                     : (nt == 2) ? b_lam
                                 : b_gate + (nt-3)*128;
    #pragma unroll
    for (int nf = 0; nf < 8; ++nf) {
        int nl = nf*16 + lr;
        float bias = bsrc[nl];
        #pragma unroll
        for (int i = 0; i < 2; ++i)
        #pragma unroll
        for (int r = 0; r < 4; ++r) {
            int m = m0 + wm + i*16 + rb + r;
            float v = acc[i][nf][r] + bias;
            float e = __expf(-v);
            float s = __builtin_amdgcn_rcpf(1.f + e);
            if (nt == 2)      OM[(size_t)m*128 + nl] = f2b(e*s);
            else if (nt < 2)  SC[(size_t)m*256 + nt*128 + nl] = f2b(v*s);
            else              GATE[(size_t)m*256 + (nt-3)*128 + nl] = f2b(v*s);
        }
    }
}

// ---------------- K2: fused fwd+rev complex scans, full-d, bf16 I/O ----------
template<int AXISW, int FIRSTPAIR>
__global__ __launch_bounds__(256) void k_scan2(const u16* __restrict__ SC,
                                               const u16* __restrict__ OM,
                                               const float* __restrict__ trig,
                                               u32* P)
{
    int j = blockIdx.x*256 + threadIdx.x;  // 131072 columns (full d)
    int d = j & 127;
    int col = j >> 7;                      // 0..1023
    int rowbase, stride;
    if (AXISW) { rowbase = (col>>3)*1024 + (col&7); stride = 8; }
    else       { rowbase = col;                     stride = 1024; }

    float cfF = trig[d],     sfF = trig[128+d];
    float cfR = trig[256+d], sfR = trig[384+d];

    long long rowF = rowbase;
    long long rowR = (long long)rowbase + (long long)stride*127;

    float hfr=0.f, hfi=0.f, hrr=0.f, hri=0.f;

    #define SCAN_STEP                                                     \
        u32 uF = *(const u32*)(SC + rowF*256 + 2*d);                      \
        float omF = b2f(OM[rowF*128 + d]);                                \
        u32 uR = *(const u32*)(SC + rowR*256 + 2*d);                      \
        float omR = b2f(OM[rowR*128 + d]);                                \
        float lamF = 1.f - omF, lamR = 1.f - omR;                         \
        float grF = lamF*cfF, giF = lamF*sfF;                             \
        float grR = lamR*cfR, giR = lamR*sfR;                             \
        float ieF = b2f((u16)(uF & 0xffff)), ioF = b2f((u16)(uF >> 16));  \
        float ieR = b2f((u16)(uR & 0xffff)), ioR = b2f((u16)(uR >> 16));  \
        float nfr = fmaf(grF, hfr, fmaf(-giF, hfi, omF*ieF));             \
        float nfi = fmaf(grF, hfi, fmaf( giF, hfr, omF*ioF));             \
        hfr = nfr; hfi = nfi;                                             \
        float nrr = fmaf(grR, hrr, fmaf(-giR, hri, omR*ieR));             \
        float nri = fmaf(grR, hri, fmaf( giR, hrr, omR*ioR));             \
        hrr = nrr; hri = nri;                                             \
        long long piF = rowF*128 + d;                                     \
        long long piR = rowR*128 + d;

    if (FIRSTPAIR) {
        #pragma unroll 4
        for (int t = 0; t < 64; ++t, rowF += stride, rowR -= stride) {
            SCAN_STEP
            P[piF] = pack2(hfr, hfi);
            P[piR] = pack2(hrr, hri);
        }
        #pragma unroll 4
        for (int t = 64; t < 128; ++t, rowF += stride, rowR -= stride) {
            SCAN_STEP
            u32 oF = P[piF];
            P[piF] = pack2(b2f((u16)(oF&0xffff)) + hfr, b2f((u16)(oF>>16)) + hfi);
            u32 oR = P[piR];
            P[piR] = pack2(b2f((u16)(oR&0xffff)) + hrr, b2f((u16)(oR>>16)) + hri);
        }
    } else {
        #pragma unroll 4
        for (int t = 0; t < 128; ++t, rowF += stride, rowR -= stride) {
            SCAN_STEP
            u32 oF = P[piF];
            P[piF] = pack2(b2f((u16)(oF&0xffff)) + hfr, b2f((u16)(oF>>16)) + hfi);
            u32 oR = P[piR];
            P[piR] = pack2(b2f((u16)(oR&0xffff)) + hrr, b2f((u16)(oR>>16)) + hri);
        }
    }
    #undef SCAN_STEP
}

// ---------------- K3: LN + gate + out GEMM via MFMA; B direct from L2 -------
// LDS = fgM only (33.8 KiB) -> 4 blocks/CU; 1 barrier. Same accumulation
// order as r18 (kk = kc*2+ks) -> bit-exact.
#define GETC(v,i) ((i)==0?(v).x:(i)==1?(v).y:(i)==2?(v).z:(v).w)
__global__ __launch_bounds__(256, 4) void k_backend_mfma(
    const uint4* __restrict__ P4, const u16* __restrict__ GATE,
    const u16* __restrict__ WoTn, const float* __restrict__ ln_w,
    const float* __restrict__ ln_b, const float* __restrict__ bo,
    float* __restrict__ out)
{
    __shared__ u16 fgM[64][264];                // 33.8 KiB bf16, [m][k], +8 pad
    int tid = threadIdx.x;
    int m0 = blockIdx.x * 64;                   // 2048 blocks
    int r = tid >> 2, q = tid & 3;              // 4 threads per row
    size_t prow4 = (size_t)(m0 + r)*32 + q*8;   // uint4 units (128 u32/row)
    size_t grow = (size_t)(m0 + r)*256;         // u16 units (GATE in ws)

    uint4 ga[4], gb[4];
    #pragma unroll
    for (int g4 = 0; g4 < 4; ++g4) {
        ga[g4] = *(const uint4*)(GATE + grow + q*32 + g4*8);
        gb[g4] = *(const uint4*)(GATE + grow + 128 + q*32 + g4*8);
    }

    uint4 pw[8];                                // 32 packed complex (bf16)
    #pragma unroll
    for (int c4 = 0; c4 < 8; ++c4) pw[c4] = P4[prow4 + c4];

    float fr_[32], fi_[32];
    #pragma unroll
    for (int c4 = 0; c4 < 8; ++c4) {
        #pragma unroll
        for (int w = 0; w < 4; ++w) {
            u32 word = GETC(pw[c4], w);
            int jj = c4*4 + w;
            fr_[jj] = b2f((u16)(word & 0xffff));
            fi_[jj] = b2f((u16)(word >> 16));
        }
    }

    float sum = 0.f, ss = 0.f;
    #pragma unroll
    for (int jj = 0; jj < 32; ++jj) {
        sum += fr_[jj] + fi_[jj];
        ss  += fr_[jj]*fr_[jj] + fi_[jj]*fi_[jj];
    }
    sum += __shfl_xor(sum, 1); sum += __shfl_xor(sum, 2);
    ss  += __shfl_xor(ss, 1);  ss  += __shfl_xor(ss, 2);
    float mu = sum * (1.f/256.f);
    float var = ss * (1.f/256.f) - mu*mu;
    float rstd = rsqrtf(var + 1e-5f);

    #pragma unroll
    for (int jj = 0; jj < 32; ++jj) {
        int pd = q*32 + jj;                     // complex channel 0..127
        int g4 = jj >> 3, e = jj & 7;
        u32 gur = GETC(ga[g4], e>>1), gui = GETC(gb[g4], e>>1);
        float gvr = b2f((u16)((e&1) ? (gur>>16) : (gur&0xffff)));
        float gvi = b2f((u16)((e&1) ? (gui>>16) : (gui&0xffff)));
        float vr = ((fr_[jj] - mu)*rstd*ln_w[pd]     + ln_b[pd])     * gvr;
        float vi = ((fi_[jj] - mu)*rstd*ln_w[128+pd] + ln_b[128+pd]) * gvi;
        fgM[r][pd]       = f2b(vr);
        fgM[r][128 + pd] = f2b(vi);
    }
    __syncthreads();

    // out[64][128] = fgM @ WoTn^T via MFMA; B frags direct from L2-hot WoTn
    int lane = tid & 63, w = tid >> 6;
    int lr = lane & 15, lk = (lane>>4)*8;
    int rb = (lane>>4)*4;

    frag_cd acc[8] = {};
    #pragma unroll
    for (int kk = 0; kk < 8; ++kk) {
        int kglob = kk*32 + lk;
        frag_ab a = *(const frag_ab*)(&fgM[w*16 + lr][kglob]);
        #pragma unroll
        for (int nf = 0; nf < 8; ++nf) {
            frag_ab b = *(const frag_ab*)(WoTn + (size_t)(nf*16+lr)*256 + kglob);
            acc[nf] = __builtin_amdgcn_mfma_f32_16x16x32_bf16(a, b, acc[nf], 0,0,0);
        }
    }

    #pragma unroll
    for (int nf = 0; nf < 8; ++nf) {
        int n = nf*16 + lr;
        float bias = bo[n];
        #pragma unroll
        for (int rr = 0; rr < 4; ++rr) {
            int m = m0 + w*16 + rb + rr;
            out[(size_t)m*128 + n] = acc[nf][rr] + bias;
        }
    }
}

// ---------------- launch -----------------------------------------------------
extern "C" void kernel_launch(void* const* d_in, const int* in_sizes, int n_in,
                              void* d_out, int out_size, void* d_ws, size_t ws_size,
                              hipStream_t stream)
{
    const float* x      = (const float*)d_in[0];
    const float* W_in   = (const float*)d_in[1];
    const float* b_in   = (const float*)d_in[2];
    const float* W_lam  = (const float*)d_in[3];
    const float* b_lam  = (const float*)d_in[4];
    const float* th_f   = (const float*)d_in[5];
    const float* th_r   = (const float*)d_in[6];
    const float* W_gate = (const float*)d_in[7];
    const float* b_gate = (const float*)d_in[8];
    const float* W_out  = (const float*)d_in[9];
    const float* b_out  = (const float*)d_in[10];
    const float* ln_w   = (const float*)d_in[11];
    const float* ln_b   = (const float*)d_in[12];

    // ws layout: 168,003,584 B <= 168,008,192 B proven-safe envelope
    char* ws = (char*)d_ws;
    u32* P     = (u32*)(ws);                      //  67,108,864 (bf16-pair, full d)
    u16* xb    = (u16*)(ws);                      //  33,554,432 ALIASES P (disjoint
                                                  //  lifetime: xb dies at front end;
                                                  //  P first written by scan1)
    u16* OM    = (u16*)(ws + 67108864LL);         //  33,554,432 (bf16 om, full d)
    u16* GATE  = (u16*)(ws + 100663296LL);        //  67,108,864 (bf16 gate)
    float* trig= (float*)(ws + 167772160LL);      //   2,048
    u16* WoTn  = (u16*)(ws + 167774208LL);        //  65,536 (bf16 W_out, n-major)
    u16* WtB   = (u16*)(ws + 167839744LL);        // 163,840 (bf16 front W, n-major)

    // d_out time-shares: SC bf16[M][256] (front->scans) -> out f32[M][128]
    u16* SC   = (u16*)d_out;
    float* out = (float*)d_out;

    hipLaunchKernelGGL(k_prep, dim3(897), dim3(128), 0, stream,
                       th_f, th_r, W_in, W_lam, W_gate, W_out, trig, WoTn, WtB);
    hipLaunchKernelGGL(k_cast, dim3(8192), dim3(256), 0, stream,
                       (const float4*)x, (uint4*)xb);

    hipLaunchKernelGGL(k_front_mfma, dim3(5120), dim3(256), 0, stream,
                       xb, WtB, b_in, b_lam, b_gate, SC, OM, GATE);

    hipLaunchKernelGGL(HIP_KERNEL_NAME(k_scan2<0,1>), dim3(512), dim3(256), 0, stream,
                       SC, OM, trig, P);
    hipLaunchKernelGGL(HIP_KERNEL_NAME(k_scan2<1,0>), dim3(512), dim3(256), 0, stream,
                       SC, OM, trig, P);

    hipLaunchKernelGGL(k_backend_mfma, dim3(2048), dim3(256), 0, stream,
                       (const uint4*)P, GATE, WoTn, ln_w, ln_b, b_out, out);
}

// Round 20
// 316.420 us; speedup vs baseline: 1.2125x; 1.2125x over previous
//
#include <hip/hip_runtime.h>
#include <hip/hip_bf16.h>
#include <math.h>

// Problem constants
#define HH 128
#define WWW 128
#define BB 8
#define MM (HH*WWW*BB)      // 131072 rows (h,w,b)

typedef unsigned int u32;
typedef unsigned short u16;

using frag_ab = __attribute__((ext_vector_type(8))) short;   // 8 bf16
using frag_cd = __attribute__((ext_vector_type(4))) float;   // 4 f32

__device__ __forceinline__ float b2f(u16 s){ return __uint_as_float(((u32)s)<<16); }
__device__ __forceinline__ u16 f2b(float f){
    u32 u = __float_as_uint(f);
    return (u16)((u + 0x7fffu + ((u>>16)&1u)) >> 16);
}
__device__ __forceinline__ u32 pack2(float lo, float hi){
    return (u32)f2b(lo) | ((u32)f2b(hi)<<16);
}

// ---------------- K0: prep: WtB (front W bf16 n-major), WoTn, trig ----------
__global__ __launch_bounds__(128) void k_prep(
    const float* __restrict__ th_f, const float* __restrict__ th_r,
    const float* __restrict__ W_in, const float* __restrict__ W_lam,
    const float* __restrict__ W_gate, const float* __restrict__ W_out,
    float* __restrict__ trig, u16* __restrict__ WoTn, u16* __restrict__ WtB)
{
    int t = blockIdx.x*128 + threadIdx.x;     // 897 blocks x 128
    if (t < 81920) {
        int n = t >> 7, k = t & 127;
        float v = (n < 256) ? W_in[k*256 + n]
                : (n < 384) ? W_lam[k*128 + (n-256)]
                            : W_gate[k*256 + (n-384)];
        WtB[t] = f2b(v);
    } else if (t < 114688) {                  // WoTn[n][k] = W_out[k][n]
        int u = t - 81920;
        int n = u >> 8, k = u & 255;
        WoTn[u] = f2b(W_out[(size_t)k*128 + n]);
    } else if (t < 114816) {
        int d = t - 114688;
        trig[d]     = cosf(th_f[d]); trig[128+d] = sinf(th_f[d]);
        trig[256+d] = cosf(th_r[d]); trig[384+d] = sinf(th_r[d]);
    }
}

// ---------------- K0b: cast x f32 -> bf16 (xb aliases P's ws space) ---------
__global__ __launch_bounds__(256) void k_cast(const float4* __restrict__ x,
                                              uint4* __restrict__ xb){
    size_t i = (size_t)blockIdx.x*256 + threadIdx.x;   // 2,097,152 threads
    float4 a = x[2*i], b = x[2*i+1];
    uint4 o;
    o.x = pack2(a.x, a.y); o.y = pack2(a.z, a.w);
    o.z = pack2(b.x, b.y); o.w = pack2(b.z, b.w);
    xb[i] = o;
}

// ---------------- K1: front GEMM via MFMA; B in LDS, A direct from L2 -------
__global__ __launch_bounds__(256, 4) void k_front_mfma(
    const u16* __restrict__ xb, const u16* __restrict__ WtB,
    const float* __restrict__ b_in, const float* __restrict__ b_lam,
    const float* __restrict__ b_gate,
    u16* __restrict__ SC, u16* __restrict__ OM, u16* __restrict__ GATE)
{
    __shared__ __align__(16) char Bs[32768];   // 128 n-rows x 256B, XOR-swizzled

    int bid = blockIdx.x;
    int mt = bid / 5, nt = bid % 5;
    int m0 = mt * 128;
    int tid = threadIdx.x;

    #pragma unroll
    for (int it = 0; it < 8; ++it) {           // stage B: raw bf16 copy
        int u = it*256 + tid;
        int row = u >> 4, c16 = u & 15;
        int dst = (row<<8) + ((c16<<4) ^ ((row&7)<<4));
        *(uint4*)(Bs + dst) =
            *(const uint4*)(WtB + (size_t)(nt*128+row)*128 + c16*8);
    }
    __syncthreads();

    int lane = tid & 63, w = tid >> 6;
    int wm = w*32;
    int lr = lane & 15, lk = (lane>>4)*8;
    int rb = (lane>>4)*4;

    const u16* a0p = xb + (size_t)(m0 + wm + lr)*128 + lk;
    const u16* a1p = a0p + 16*128;

    frag_cd acc[2][8] = {};
    #pragma unroll
    for (int kt = 0; kt < 4; ++kt) {
        frag_ab a0 = *(const frag_ab*)(a0p + kt*32);
        frag_ab a1 = *(const frag_ab*)(a1p + kt*32);
        int kb2 = (kt*32 + lk)*2;
        #pragma unroll
        for (int nf = 0; nf < 8; ++nf) {
            int rn = nf*16 + lr;
            frag_ab bf = *(const frag_ab*)(Bs + (rn<<8) + (kb2 ^ ((rn&7)<<4)));
            acc[0][nf] = __builtin_amdgcn_mfma_f32_16x16x32_bf16(a0, bf, acc[0][nf], 0,0,0);
            acc[1][nf] = __builtin_amdgcn_mfma_f32_16x16x32_bf16(a1, bf, acc[1][nf], 0,0,0);
        }
    }

    const float* bsrc = (nt < 2) ? b_in + nt*128
                     : (nt == 2) ? b_lam
                                 : b_gate + (nt-3)*128;
    #pragma unroll
    for (int nf = 0; nf < 8; ++nf) {
        int nl = nf*16 + lr;
        float bias = bsrc[nl];
        #pragma unroll
        for (int i = 0; i < 2; ++i)
        #pragma unroll
        for (int r = 0; r < 4; ++r) {
            int m = m0 + wm + i*16 + rb + r;
            float v = acc[i][nf][r] + bias;
            float e = __expf(-v);
            float s = __builtin_amdgcn_rcpf(1.f + e);
            if (nt == 2)      OM[(size_t)m*128 + nl] = f2b(e*s);
            else if (nt < 2)  SC[(size_t)m*256 + nt*128 + nl] = f2b(v*s);
            else              GATE[(size_t)m*256 + (nt-3)*128 + nl] = f2b(v*s);
        }
    }
}

// ---------------- K2: fused fwd+rev complex scans, full-d, bf16 I/O ----------
template<int AXISW, int FIRSTPAIR>
__global__ __launch_bounds__(256) void k_scan2(const u16* __restrict__ SC,
                                               const u16* __restrict__ OM,
                                               const float* __restrict__ trig,
                                               u32* P)
{
    int j = blockIdx.x*256 + threadIdx.x;  // 131072 columns (full d)
    int d = j & 127;
    int col = j >> 7;                      // 0..1023
    int rowbase, stride;
    if (AXISW) { rowbase = (col>>3)*1024 + (col&7); stride = 8; }
    else       { rowbase = col;                     stride = 1024; }

    float cfF = trig[d],     sfF = trig[128+d];
    float cfR = trig[256+d], sfR = trig[384+d];

    long long rowF = rowbase;
    long long rowR = (long long)rowbase + (long long)stride*127;

    float hfr=0.f, hfi=0.f, hrr=0.f, hri=0.f;

    #define SCAN_STEP                                                     \
        u32 uF = *(const u32*)(SC + rowF*256 + 2*d);                      \
        float omF = b2f(OM[rowF*128 + d]);                                \
        u32 uR = *(const u32*)(SC + rowR*256 + 2*d);                      \
        float omR = b2f(OM[rowR*128 + d]);                                \
        float lamF = 1.f - omF, lamR = 1.f - omR;                         \
        float grF = lamF*cfF, giF = lamF*sfF;                             \
        float grR = lamR*cfR, giR = lamR*sfR;                             \
        float ieF = b2f((u16)(uF & 0xffff)), ioF = b2f((u16)(uF >> 16));  \
        float ieR = b2f((u16)(uR & 0xffff)), ioR = b2f((u16)(uR >> 16));  \
        float nfr = fmaf(grF, hfr, fmaf(-giF, hfi, omF*ieF));             \
        float nfi = fmaf(grF, hfi, fmaf( giF, hfr, omF*ioF));             \
        hfr = nfr; hfi = nfi;                                             \
        float nrr = fmaf(grR, hrr, fmaf(-giR, hri, omR*ieR));             \
        float nri = fmaf(grR, hri, fmaf( giR, hrr, omR*ioR));             \
        hrr = nrr; hri = nri;                                             \
        long long piF = rowF*128 + d;                                     \
        long long piR = rowR*128 + d;

    if (FIRSTPAIR) {
        #pragma unroll 8
        for (int t = 0; t < 64; ++t, rowF += stride, rowR -= stride) {
            SCAN_STEP
            P[piF] = pack2(hfr, hfi);
            P[piR] = pack2(hrr, hri);
        }
        #pragma unroll 8
        for (int t = 64; t < 128; ++t, rowF += stride, rowR -= stride) {
            SCAN_STEP
            u32 oF = P[piF];
            P[piF] = pack2(b2f((u16)(oF&0xffff)) + hfr, b2f((u16)(oF>>16)) + hfi);
            u32 oR = P[piR];
            P[piR] = pack2(b2f((u16)(oR&0xffff)) + hrr, b2f((u16)(oR>>16)) + hri);
        }
    } else {
        #pragma unroll 8
        for (int t = 0; t < 128; ++t, rowF += stride, rowR -= stride) {
            SCAN_STEP
            u32 oF = P[piF];
            P[piF] = pack2(b2f((u16)(oF&0xffff)) + hfr, b2f((u16)(oF>>16)) + hfi);
            u32 oR = P[piR];
            P[piR] = pack2(b2f((u16)(oR&0xffff)) + hrr, b2f((u16)(oR>>16)) + hri);
        }
    }
    #undef SCAN_STEP
}

// ---------------- K3: LN + gate + out GEMM via MFMA (r18-proven, staged B) --
#define GETC(v,i) ((i)==0?(v).x:(i)==1?(v).y:(i)==2?(v).z:(v).w)
__global__ __launch_bounds__(256) void k_backend_mfma(
    const uint4* __restrict__ P4, const u16* __restrict__ GATE,
    const u16* __restrict__ WoTn, const float* __restrict__ ln_w,
    const float* __restrict__ ln_b, const float* __restrict__ bo,
    float* __restrict__ out)
{
    __shared__ u16 fgM[64][264];                // 33.8 KiB bf16, [m][k], +8 pad
    __shared__ __align__(16) char wBs[16384];   // 16 KiB: B chunk [n][64k] swz
    int tid = threadIdx.x;
    int m0 = blockIdx.x * 64;                   // 2048 blocks
    int r = tid >> 2, q = tid & 3;              // 4 threads per row
    size_t prow4 = (size_t)(m0 + r)*32 + q*8;   // uint4 units (128 u32/row)
    size_t grow = (size_t)(m0 + r)*256;         // u16 units (GATE in ws)

    uint4 ga[4], gb[4];
    #pragma unroll
    for (int g4 = 0; g4 < 4; ++g4) {
        ga[g4] = *(const uint4*)(GATE + grow + q*32 + g4*8);
        gb[g4] = *(const uint4*)(GATE + grow + 128 + q*32 + g4*8);
    }

    uint4 pw[8];                                // 32 packed complex (bf16)
    #pragma unroll
    for (int c4 = 0; c4 < 8; ++c4) pw[c4] = P4[prow4 + c4];

    float fr_[32], fi_[32];
    #pragma unroll
    for (int c4 = 0; c4 < 8; ++c4) {
        #pragma unroll
        for (int w = 0; w < 4; ++w) {
            u32 word = GETC(pw[c4], w);
            int jj = c4*4 + w;
            fr_[jj] = b2f((u16)(word & 0xffff));
            fi_[jj] = b2f((u16)(word >> 16));
        }
    }

    float sum = 0.f, ss = 0.f;
    #pragma unroll
    for (int jj = 0; jj < 32; ++jj) {
        sum += fr_[jj] + fi_[jj];
        ss  += fr_[jj]*fr_[jj] + fi_[jj]*fi_[jj];
    }
    sum += __shfl_xor(sum, 1); sum += __shfl_xor(sum, 2);
    ss  += __shfl_xor(ss, 1);  ss  += __shfl_xor(ss, 2);
    float mu = sum * (1.f/256.f);
    float var = ss * (1.f/256.f) - mu*mu;
    float rstd = rsqrtf(var + 1e-5f);

    #pragma unroll
    for (int jj = 0; jj < 32; ++jj) {
        int pd = q*32 + jj;                     // complex channel 0..127
        int g4 = jj >> 3, e = jj & 7;
        u32 gur = GETC(ga[g4], e>>1), gui = GETC(gb[g4], e>>1);
        float gvr = b2f((u16)((e&1) ? (gur>>16) : (gur&0xffff)));
        float gvi = b2f((u16)((e&1) ? (gui>>16) : (gui&0xffff)));
        float vr = ((fr_[jj] - mu)*rstd*ln_w[pd]     + ln_b[pd])     * gvr;
        float vi = ((fi_[jj] - mu)*rstd*ln_w[128+pd] + ln_b[128+pd]) * gvi;
        fgM[r][pd]       = f2b(vr);
        fgM[r][128 + pd] = f2b(vi);
    }

    // out[64][128] = fgM @ WoTn^T via MFMA; wave w owns rows w*16..w*16+15
    int lane = tid & 63, w = tid >> 6;
    int lr = lane & 15, lk = (lane>>4)*8;
    int rb = (lane>>4)*4;

    frag_cd acc[8] = {};
    for (int kc = 0; kc < 4; ++kc) {
        __syncthreads();                        // fgM ready / prev wBs reads done
        #pragma unroll
        for (int it = 0; it < 4; ++it) {        // stage B chunk: 128n x 64k bf16
            int u = it*256 + tid;               // 1024 uint4 units
            int n = u >> 3, c8 = u & 7;
            int dst = (n<<7) + ((c8<<4) ^ ((n&7)<<4));
            *(uint4*)(wBs + dst) =
                *(const uint4*)(WoTn + (size_t)n*256 + kc*64 + c8*8);
        }
        __syncthreads();

        #pragma unroll
        for (int ks = 0; ks < 2; ++ks) {
            int kglob = kc*64 + ks*32 + lk;
            frag_ab a = *(const frag_ab*)(&fgM[w*16 + lr][kglob]);
            int kb2 = (ks*32 + lk)*2;           // byte offset in 128B row
            #pragma unroll
            for (int nf = 0; nf < 8; ++nf) {
                int rn = nf*16 + lr;
                frag_ab b = *(const frag_ab*)(wBs + (rn<<7) + (kb2 ^ ((rn&7)<<4)));
                acc[nf] = __builtin_amdgcn_mfma_f32_16x16x32_bf16(a, b, acc[nf], 0,0,0);
            }
        }
    }

    #pragma unroll
    for (int nf = 0; nf < 8; ++nf) {
        int n = nf*16 + lr;
        float bias = bo[n];
        #pragma unroll
        for (int rr = 0; rr < 4; ++rr) {
            int m = m0 + w*16 + rb + rr;
            out[(size_t)m*128 + n] = acc[nf][rr] + bias;
        }
    }
}

// ---------------- launch -----------------------------------------------------
extern "C" void kernel_launch(void* const* d_in, const int* in_sizes, int n_in,
                              void* d_out, int out_size, void* d_ws, size_t ws_size,
                              hipStream_t stream)
{
    const float* x      = (const float*)d_in[0];
    const float* W_in   = (const float*)d_in[1];
    const float* b_in   = (const float*)d_in[2];
    const float* W_lam  = (const float*)d_in[3];
    const float* b_lam  = (const float*)d_in[4];
    const float* th_f   = (const float*)d_in[5];
    const float* th_r   = (const float*)d_in[6];
    const float* W_gate = (const float*)d_in[7];
    const float* b_gate = (const float*)d_in[8];
    const float* W_out  = (const float*)d_in[9];
    const float* b_out  = (const float*)d_in[10];
    const float* ln_w   = (const float*)d_in[11];
    const float* ln_b   = (const float*)d_in[12];

    // ws layout: 168,003,584 B <= 168,008,192 B proven-safe envelope
    char* ws = (char*)d_ws;
    u32* P     = (u32*)(ws);                      //  67,108,864 (bf16-pair, full d)
    u16* xb    = (u16*)(ws);                      //  33,554,432 ALIASES P (disjoint
                                                  //  lifetime: xb dies at front end;
                                                  //  P first written by scan1)
    u16* OM    = (u16*)(ws + 67108864LL);         //  33,554,432 (bf16 om, full d)
    u16* GATE  = (u16*)(ws + 100663296LL);        //  67,108,864 (bf16 gate)
    float* trig= (float*)(ws + 167772160LL);      //   2,048
    u16* WoTn  = (u16*)(ws + 167774208LL);        //  65,536 (bf16 W_out, n-major)
    u16* WtB   = (u16*)(ws + 167839744LL);        // 163,840 (bf16 front W, n-major)

    // d_out time-shares: SC bf16[M][256] (front->scans) -> out f32[M][128]
    u16* SC   = (u16*)d_out;
    float* out = (float*)d_out;

    hipLaunchKernelGGL(k_prep, dim3(897), dim3(128), 0, stream,
                       th_f, th_r, W_in, W_lam, W_gate, W_out, trig, WoTn, WtB);
    hipLaunchKernelGGL(k_cast, dim3(8192), dim3(256), 0, stream,
                       (const float4*)x, (uint4*)xb);

    hipLaunchKernelGGL(k_front_mfma, dim3(5120), dim3(256), 0, stream,
                       xb, WtB, b_in, b_lam, b_gate, SC, OM, GATE);

    hipLaunchKernelGGL(HIP_KERNEL_NAME(k_scan2<0,1>), dim3(512), dim3(256), 0, stream,
                       SC, OM, trig, P);
    hipLaunchKernelGGL(HIP_KERNEL_NAME(k_scan2<1,0>), dim3(512), dim3(256), 0, stream,
                       SC, OM, trig, P);

    hipLaunchKernelGGL(k_backend_mfma, dim3(2048), dim3(256), 0, stream,
                       (const uint4*)P, GATE, WoTn, ln_w, ln_b, b_out, out);
}

// Round 21
// 300.401 us; speedup vs baseline: 1.2772x; 1.0533x over previous
//
#include <hip/hip_runtime.h>
#include <hip/hip_bf16.h>
#include <math.h>

// Problem constants
#define HH 128
#define WWW 128
#define BB 8
#define MM (HH*WWW*BB)      // 131072 rows (h,w,b)

typedef unsigned int u32;
typedef unsigned short u16;

using frag_ab = __attribute__((ext_vector_type(8))) short;   // 8 bf16
using frag_cd = __attribute__((ext_vector_type(4))) float;   // 4 f32

__device__ __forceinline__ float b2f(u16 s){ return __uint_as_float(((u32)s)<<16); }
__device__ __forceinline__ u16 f2b(float f){
    u32 u = __float_as_uint(f);
    return (u16)((u + 0x7fffu + ((u>>16)&1u)) >> 16);
}
__device__ __forceinline__ u32 pack2(float lo, float hi){
    return (u32)f2b(lo) | ((u32)f2b(hi)<<16);
}

// ---------------- K0: prep: WtB (front W bf16 n-major), WoTn, trig ----------
__global__ __launch_bounds__(128) void k_prep(
    const float* __restrict__ th_f, const float* __restrict__ th_r,
    const float* __restrict__ W_in, const float* __restrict__ W_lam,
    const float* __restrict__ W_gate, const float* __restrict__ W_out,
    float* __restrict__ trig, u16* __restrict__ WoTn, u16* __restrict__ WtB)
{
    int t = blockIdx.x*128 + threadIdx.x;     // 897 blocks x 128
    if (t < 81920) {
        int n = t >> 7, k = t & 127;
        float v = (n < 256) ? W_in[k*256 + n]
                : (n < 384) ? W_lam[k*128 + (n-256)]
                            : W_gate[k*256 + (n-384)];
        WtB[t] = f2b(v);
    } else if (t < 114688) {                  // WoTn[n][k] = W_out[k][n]
        int u = t - 81920;
        int n = u >> 8, k = u & 255;
        WoTn[u] = f2b(W_out[(size_t)k*128 + n]);
    } else if (t < 114816) {
        int d = t - 114688;
        trig[d]     = cosf(th_f[d]); trig[128+d] = sinf(th_f[d]);
        trig[256+d] = cosf(th_r[d]); trig[384+d] = sinf(th_r[d]);
    }
}

// ---------------- K0b: cast x f32 -> bf16 (xb aliases P's ws space) ---------
__global__ __launch_bounds__(256) void k_cast(const float4* __restrict__ x,
                                              uint4* __restrict__ xb){
    size_t i = (size_t)blockIdx.x*256 + threadIdx.x;   // 2,097,152 threads
    float4 a = x[2*i], b = x[2*i+1];
    uint4 o;
    o.x = pack2(a.x, a.y); o.y = pack2(a.z, a.w);
    o.z = pack2(b.x, b.y); o.w = pack2(b.z, b.w);
    xb[i] = o;
}

// ---------------- K1: front GEMM via MFMA; B in LDS, A direct from L2 -------
// Output staged through LDS (reusing Bs space) for fully-coalesced stores.
__global__ __launch_bounds__(256, 4) void k_front_mfma(
    const u16* __restrict__ xb, const u16* __restrict__ WtB,
    const float* __restrict__ b_in, const float* __restrict__ b_lam,
    const float* __restrict__ b_gate,
    u16* __restrict__ SC, u16* __restrict__ OM, u16* __restrict__ GATE)
{
    // 34,816 B: B-staging uses first 32 KiB (row<<8 swizzled);
    // after MFMAs it is reused as out-stage [128 rows][272 B stride].
    __shared__ __align__(16) char smem[34816];

    int bid = blockIdx.x;
    int mt = bid / 5, nt = bid % 5;
    int m0 = mt * 128;
    int tid = threadIdx.x;

    #pragma unroll
    for (int it = 0; it < 8; ++it) {           // stage B: raw bf16 copy
        int u = it*256 + tid;
        int row = u >> 4, c16 = u & 15;
        int dst = (row<<8) + ((c16<<4) ^ ((row&7)<<4));
        *(uint4*)(smem + dst) =
            *(const uint4*)(WtB + (size_t)(nt*128+row)*128 + c16*8);
    }
    __syncthreads();

    int lane = tid & 63, w = tid >> 6;
    int wm = w*32;
    int lr = lane & 15, lk = (lane>>4)*8;
    int rb = (lane>>4)*4;

    const u16* a0p = xb + (size_t)(m0 + wm + lr)*128 + lk;
    const u16* a1p = a0p + 16*128;

    frag_cd acc[2][8] = {};
    #pragma unroll
    for (int kt = 0; kt < 4; ++kt) {
        frag_ab a0 = *(const frag_ab*)(a0p + kt*32);
        frag_ab a1 = *(const frag_ab*)(a1p + kt*32);
        int kb2 = (kt*32 + lk)*2;
        #pragma unroll
        for (int nf = 0; nf < 8; ++nf) {
            int rn = nf*16 + lr;
            frag_ab bf = *(const frag_ab*)(smem + (rn<<8) + (kb2 ^ ((rn&7)<<4)));
            acc[0][nf] = __builtin_amdgcn_mfma_f32_16x16x32_bf16(a0, bf, acc[0][nf], 0,0,0);
            acc[1][nf] = __builtin_amdgcn_mfma_f32_16x16x32_bf16(a1, bf, acc[1][nf], 0,0,0);
        }
    }
    __syncthreads();                           // all Bs reads done; reuse as out-stage

    const float* bsrc = (nt < 2) ? b_in + nt*128
                     : (nt == 2) ? b_lam
                                 : b_gate + (nt-3)*128;
    #pragma unroll
    for (int nf = 0; nf < 8; ++nf) {
        int nl = nf*16 + lr;
        float bias = bsrc[nl];
        #pragma unroll
        for (int i = 0; i < 2; ++i)
        #pragma unroll
        for (int r = 0; r < 4; ++r) {
            int ml = wm + i*16 + rb + r;       // local row 0..127
            float v = acc[i][nf][r] + bias;
            float e = __expf(-v);
            float s = __builtin_amdgcn_rcpf(1.f + e);
            float outv = (nt == 2) ? e*s : v*s;
            *(u16*)(smem + ml*272 + nl*2) = f2b(outv);
        }
    }
    __syncthreads();

    #pragma unroll
    for (int it = 0; it < 8; ++it) {           // coalesced store: 2048 uint4
        int u = it*256 + tid;
        int row = u >> 4, c16 = u & 15;
        uint4 v = *(const uint4*)(smem + row*272 + c16*16);
        int m = m0 + row;
        if (nt < 2)
            *(uint4*)(&SC[(size_t)m*256 + nt*128 + c16*8]) = v;
        else if (nt == 2)
            *(uint4*)(&OM[(size_t)m*128 + c16*8]) = v;
        else
            *(uint4*)(&GATE[(size_t)m*256 + (nt-3)*128 + c16*8]) = v;
    }
}

// ---------------- K2: fused fwd+rev complex scans, full-d, bf16 I/O ----------
template<int AXISW, int FIRSTPAIR>
__global__ __launch_bounds__(256) void k_scan2(const u16* __restrict__ SC,
                                               const u16* __restrict__ OM,
                                               const float* __restrict__ trig,
                                               u32* P)
{
    int j = blockIdx.x*256 + threadIdx.x;  // 131072 columns (full d)
    int d = j & 127;
    int col = j >> 7;                      // 0..1023
    int rowbase, stride;
    if (AXISW) { rowbase = (col>>3)*1024 + (col&7); stride = 8; }
    else       { rowbase = col;                     stride = 1024; }

    float cfF = trig[d],     sfF = trig[128+d];
    float cfR = trig[256+d], sfR = trig[384+d];

    long long rowF = rowbase;
    long long rowR = (long long)rowbase + (long long)stride*127;

    float hfr=0.f, hfi=0.f, hrr=0.f, hri=0.f;

    #define SCAN_STEP                                                     \
        u32 uF = *(const u32*)(SC + rowF*256 + 2*d);                      \
        float omF = b2f(OM[rowF*128 + d]);                                \
        u32 uR = *(const u32*)(SC + rowR*256 + 2*d);                      \
        float omR = b2f(OM[rowR*128 + d]);                                \
        float lamF = 1.f - omF, lamR = 1.f - omR;                         \
        float grF = lamF*cfF, giF = lamF*sfF;                             \
        float grR = lamR*cfR, giR = lamR*sfR;                             \
        float ieF = b2f((u16)(uF & 0xffff)), ioF = b2f((u16)(uF >> 16));  \
        float ieR = b2f((u16)(uR & 0xffff)), ioR = b2f((u16)(uR >> 16));  \
        float nfr = fmaf(grF, hfr, fmaf(-giF, hfi, omF*ieF));             \
        float nfi = fmaf(grF, hfi, fmaf( giF, hfr, omF*ioF));             \
        hfr = nfr; hfi = nfi;                                             \
        float nrr = fmaf(grR, hrr, fmaf(-giR, hri, omR*ieR));             \
        float nri = fmaf(grR, hri, fmaf( giR, hrr, omR*ioR));             \
        hrr = nrr; hri = nri;                                             \
        long long piF = rowF*128 + d;                                     \
        long long piR = rowR*128 + d;

    if (FIRSTPAIR) {
        #pragma unroll 8
        for (int t = 0; t < 64; ++t, rowF += stride, rowR -= stride) {
            SCAN_STEP
            P[piF] = pack2(hfr, hfi);
            P[piR] = pack2(hrr, hri);
        }
        #pragma unroll 8
        for (int t = 64; t < 128; ++t, rowF += stride, rowR -= stride) {
            SCAN_STEP
            u32 oF = P[piF];
            P[piF] = pack2(b2f((u16)(oF&0xffff)) + hfr, b2f((u16)(oF>>16)) + hfi);
            u32 oR = P[piR];
            P[piR] = pack2(b2f((u16)(oR&0xffff)) + hrr, b2f((u16)(oR>>16)) + hri);
        }
    } else {
        #pragma unroll 8
        for (int t = 0; t < 128; ++t, rowF += stride, rowR -= stride) {
            SCAN_STEP
            u32 oF = P[piF];
            P[piF] = pack2(b2f((u16)(oF&0xffff)) + hfr, b2f((u16)(oF>>16)) + hfi);
            u32 oR = P[piR];
            P[piR] = pack2(b2f((u16)(oR&0xffff)) + hrr, b2f((u16)(oR>>16)) + hri);
        }
    }
    #undef SCAN_STEP
}

// ---------------- K3: LN + gate + out GEMM via MFMA (r18-proven, staged B) --
#define GETC(v,i) ((i)==0?(v).x:(i)==1?(v).y:(i)==2?(v).z:(v).w)
__global__ __launch_bounds__(256) void k_backend_mfma(
    const uint4* __restrict__ P4, const u16* __restrict__ GATE,
    const u16* __restrict__ WoTn, const float* __restrict__ ln_w,
    const float* __restrict__ ln_b, const float* __restrict__ bo,
    float* __restrict__ out)
{
    __shared__ u16 fgM[64][264];                // 33.8 KiB bf16, [m][k], +8 pad
    __shared__ __align__(16) char wBs[16384];   // 16 KiB: B chunk [n][64k] swz
    int tid = threadIdx.x;
    int m0 = blockIdx.x * 64;                   // 2048 blocks
    int r = tid >> 2, q = tid & 3;              // 4 threads per row
    size_t prow4 = (size_t)(m0 + r)*32 + q*8;   // uint4 units (128 u32/row)
    size_t grow = (size_t)(m0 + r)*256;         // u16 units (GATE in ws)

    uint4 ga[4], gb[4];
    #pragma unroll
    for (int g4 = 0; g4 < 4; ++g4) {
        ga[g4] = *(const uint4*)(GATE + grow + q*32 + g4*8);
        gb[g4] = *(const uint4*)(GATE + grow + 128 + q*32 + g4*8);
    }

    uint4 pw[8];                                // 32 packed complex (bf16)
    #pragma unroll
    for (int c4 = 0; c4 < 8; ++c4) pw[c4] = P4[prow4 + c4];

    float fr_[32], fi_[32];
    #pragma unroll
    for (int c4 = 0; c4 < 8; ++c4) {
        #pragma unroll
        for (int w = 0; w < 4; ++w) {
            u32 word = GETC(pw[c4], w);
            int jj = c4*4 + w;
            fr_[jj] = b2f((u16)(word & 0xffff));
            fi_[jj] = b2f((u16)(word >> 16));
        }
    }

    float sum = 0.f, ss = 0.f;
    #pragma unroll
    for (int jj = 0; jj < 32; ++jj) {
        sum += fr_[jj] + fi_[jj];
        ss  += fr_[jj]*fr_[jj] + fi_[jj]*fi_[jj];
    }
    sum += __shfl_xor(sum, 1); sum += __shfl_xor(sum, 2);
    ss  += __shfl_xor(ss, 1);  ss  += __shfl_xor(ss, 2);
    float mu = sum * (1.f/256.f);
    float var = ss * (1.f/256.f) - mu*mu;
    float rstd = rsqrtf(var + 1e-5f);

    #pragma unroll
    for (int jj = 0; jj < 32; ++jj) {
        int pd = q*32 + jj;                     // complex channel 0..127
        int g4 = jj >> 3, e = jj & 7;
        u32 gur = GETC(ga[g4], e>>1), gui = GETC(gb[g4], e>>1);
        float gvr = b2f((u16)((e&1) ? (gur>>16) : (gur&0xffff)));
        float gvi = b2f((u16)((e&1) ? (gui>>16) : (gui&0xffff)));
        float vr = ((fr_[jj] - mu)*rstd*ln_w[pd]     + ln_b[pd])     * gvr;
        float vi = ((fi_[jj] - mu)*rstd*ln_w[128+pd] + ln_b[128+pd]) * gvi;
        fgM[r][pd]       = f2b(vr);
        fgM[r][128 + pd] = f2b(vi);
    }

    // out[64][128] = fgM @ WoTn^T via MFMA; wave w owns rows w*16..w*16+15
    int lane = tid & 63, w = tid >> 6;
    int lr = lane & 15, lk = (lane>>4)*8;
    int rb = (lane>>4)*4;

    frag_cd acc[8] = {};
    for (int kc = 0; kc < 4; ++kc) {
        __syncthreads();                        // fgM ready / prev wBs reads done
        #pragma unroll
        for (int it = 0; it < 4; ++it) {        // stage B chunk: 128n x 64k bf16
            int u = it*256 + tid;               // 1024 uint4 units
            int n = u >> 3, c8 = u & 7;
            int dst = (n<<7) + ((c8<<4) ^ ((n&7)<<4));
            *(uint4*)(wBs + dst) =
                *(const uint4*)(WoTn + (size_t)n*256 + kc*64 + c8*8);
        }
        __syncthreads();

        #pragma unroll
        for (int ks = 0; ks < 2; ++ks) {
            int kglob = kc*64 + ks*32 + lk;
            frag_ab a = *(const frag_ab*)(&fgM[w*16 + lr][kglob]);
            int kb2 = (ks*32 + lk)*2;           // byte offset in 128B row
            #pragma unroll
            for (int nf = 0; nf < 8; ++nf) {
                int rn = nf*16 + lr;
                frag_ab b = *(const frag_ab*)(wBs + (rn<<7) + (kb2 ^ ((rn&7)<<4)));
                acc[nf] = __builtin_amdgcn_mfma_f32_16x16x32_bf16(a, b, acc[nf], 0,0,0);
            }
        }
    }

    #pragma unroll
    for (int nf = 0; nf < 8; ++nf) {
        int n = nf*16 + lr;
        float bias = bo[n];
        #pragma unroll
        for (int rr = 0; rr < 4; ++rr) {
            int m = m0 + w*16 + rb + rr;
            out[(size_t)m*128 + n] = acc[nf][rr] + bias;
        }
    }
}

// ---------------- launch -----------------------------------------------------
extern "C" void kernel_launch(void* const* d_in, const int* in_sizes, int n_in,
                              void* d_out, int out_size, void* d_ws, size_t ws_size,
                              hipStream_t stream)
{
    const float* x      = (const float*)d_in[0];
    const float* W_in   = (const float*)d_in[1];
    const float* b_in   = (const float*)d_in[2];
    const float* W_lam  = (const float*)d_in[3];
    const float* b_lam  = (const float*)d_in[4];
    const float* th_f   = (const float*)d_in[5];
    const float* th_r   = (const float*)d_in[6];
    const float* W_gate = (const float*)d_in[7];
    const float* b_gate = (const float*)d_in[8];
    const float* W_out  = (const float*)d_in[9];
    const float* b_out  = (const float*)d_in[10];
    const float* ln_w   = (const float*)d_in[11];
    const float* ln_b   = (const float*)d_in[12];

    // ws layout: 168,003,584 B <= 168,008,192 B proven-safe envelope
    char* ws = (char*)d_ws;
    u32* P     = (u32*)(ws);                      //  67,108,864 (bf16-pair, full d)
    u16* xb    = (u16*)(ws);                      //  33,554,432 ALIASES P (disjoint
                                                  //  lifetime: xb dies at front end;
                                                  //  P first written by scan1)
    u16* OM    = (u16*)(ws + 67108864LL);         //  33,554,432 (bf16 om, full d)
    u16* GATE  = (u16*)(ws + 100663296LL);        //  67,108,864 (bf16 gate)
    float* trig= (float*)(ws + 167772160LL);      //   2,048
    u16* WoTn  = (u16*)(ws + 167774208LL);        //  65,536 (bf16 W_out, n-major)
    u16* WtB   = (u16*)(ws + 167839744LL);        // 163,840 (bf16 front W, n-major)

    // d_out time-shares: SC bf16[M][256] (front->scans) -> out f32[M][128]
    u16* SC   = (u16*)d_out;
    float* out = (float*)d_out;

    hipLaunchKernelGGL(k_prep, dim3(897), dim3(128), 0, stream,
                       th_f, th_r, W_in, W_lam, W_gate, W_out, trig, WoTn, WtB);
    hipLaunchKernelGGL(k_cast, dim3(8192), dim3(256), 0, stream,
                       (const float4*)x, (uint4*)xb);

    hipLaunchKernelGGL(k_front_mfma, dim3(5120), dim3(256), 0, stream,
                       xb, WtB, b_in, b_lam, b_gate, SC, OM, GATE);

    hipLaunchKernelGGL(HIP_KERNEL_NAME(k_scan2<0,1>), dim3(512), dim3(256), 0, stream,
                       SC, OM, trig, P);
    hipLaunchKernelGGL(HIP_KERNEL_NAME(k_scan2<1,0>), dim3(512), dim3(256), 0, stream,
                       SC, OM, trig, P);

    hipLaunchKernelGGL(k_backend_mfma, dim3(2048), dim3(256), 0, stream,
                       (const uint4*)P, GATE, WoTn, ln_w, ln_b, b_out, out);
}

// Round 22
// 265.562 us; speedup vs baseline: 1.4447x; 1.1312x over previous
//
#include <hip/hip_runtime.h>
#include <hip/hip_bf16.h>
#include <math.h>

// Problem constants
#define HH 128
#define WWW 128
#define BB 8
#define MM (HH*WWW*BB)      // 131072 rows (h,w,b)

typedef unsigned int u32;
typedef unsigned short u16;

using frag_ab = __attribute__((ext_vector_type(8))) short;   // 8 bf16
using frag_cd = __attribute__((ext_vector_type(4))) float;   // 4 f32

__device__ __forceinline__ float b2f(u16 s){ return __uint_as_float(((u32)s)<<16); }
__device__ __forceinline__ u16 f2b(float f){
    u32 u = __float_as_uint(f);
    return (u16)((u + 0x7fffu + ((u>>16)&1u)) >> 16);
}
__device__ __forceinline__ u32 pack2(float lo, float hi){
    return (u32)f2b(lo) | ((u32)f2b(hi)<<16);
}

// ---------------- K0: prep: WtB (front W bf16 n-major), WoTn, trig ----------
__global__ __launch_bounds__(128) void k_prep(
    const float* __restrict__ th_f, const float* __restrict__ th_r,
    const float* __restrict__ W_in, const float* __restrict__ W_lam,
    const float* __restrict__ W_gate, const float* __restrict__ W_out,
    float* __restrict__ trig, u16* __restrict__ WoTn, u16* __restrict__ WtB)
{
    int t = blockIdx.x*128 + threadIdx.x;     // 897 blocks x 128
    if (t < 81920) {
        int n = t >> 7, k = t & 127;
        float v = (n < 256) ? W_in[k*256 + n]
                : (n < 384) ? W_lam[k*128 + (n-256)]
                            : W_gate[k*256 + (n-384)];
        WtB[t] = f2b(v);
    } else if (t < 114688) {                  // WoTn[n][k] = W_out[k][n]
        int u = t - 81920;
        int n = u >> 8, k = u & 255;
        WoTn[u] = f2b(W_out[(size_t)k*128 + n]);
    } else if (t < 114816) {
        int d = t - 114688;
        trig[d]     = cosf(th_f[d]); trig[128+d] = sinf(th_f[d]);
        trig[256+d] = cosf(th_r[d]); trig[384+d] = sinf(th_r[d]);
    }
}

// ---------------- K0b: cast x f32 -> bf16 (xb aliases P's ws space) ---------
__global__ __launch_bounds__(256) void k_cast(const float4* __restrict__ x,
                                              uint4* __restrict__ xb){
    size_t i = (size_t)blockIdx.x*256 + threadIdx.x;   // 2,097,152 threads
    float4 a = x[2*i], b = x[2*i+1];
    uint4 o;
    o.x = pack2(a.x, a.y); o.y = pack2(a.z, a.w);
    o.z = pack2(b.x, b.y); o.w = pack2(b.z, b.w);
    xb[i] = o;
}

// ---------------- K1: front GEMM via MFMA; B in LDS, A direct from L2 -------
// Output staged through LDS (reusing Bs space) for fully-coalesced stores.
__global__ __launch_bounds__(256, 4) void k_front_mfma(
    const u16* __restrict__ xb, const u16* __restrict__ WtB,
    const float* __restrict__ b_in, const float* __restrict__ b_lam,
    const float* __restrict__ b_gate,
    u16* __restrict__ SC, u16* __restrict__ OM, u16* __restrict__ GATE)
{
    __shared__ __align__(16) char smem[34816];

    int bid = blockIdx.x;
    int mt = bid / 5, nt = bid % 5;
    int m0 = mt * 128;
    int tid = threadIdx.x;

    #pragma unroll
    for (int it = 0; it < 8; ++it) {           // stage B: raw bf16 copy
        int u = it*256 + tid;
        int row = u >> 4, c16 = u & 15;
        int dst = (row<<8) + ((c16<<4) ^ ((row&7)<<4));
        *(uint4*)(smem + dst) =
            *(const uint4*)(WtB + (size_t)(nt*128+row)*128 + c16*8);
    }
    __syncthreads();

    int lane = tid & 63, w = tid >> 6;
    int wm = w*32;
    int lr = lane & 15, lk = (lane>>4)*8;
    int rb = (lane>>4)*4;

    const u16* a0p = xb + (size_t)(m0 + wm + lr)*128 + lk;
    const u16* a1p = a0p + 16*128;

    frag_cd acc[2][8] = {};
    #pragma unroll
    for (int kt = 0; kt < 4; ++kt) {
        frag_ab a0 = *(const frag_ab*)(a0p + kt*32);
        frag_ab a1 = *(const frag_ab*)(a1p + kt*32);
        int kb2 = (kt*32 + lk)*2;
        #pragma unroll
        for (int nf = 0; nf < 8; ++nf) {
            int rn = nf*16 + lr;
            frag_ab bf = *(const frag_ab*)(smem + (rn<<8) + (kb2 ^ ((rn&7)<<4)));
            acc[0][nf] = __builtin_amdgcn_mfma_f32_16x16x32_bf16(a0, bf, acc[0][nf], 0,0,0);
            acc[1][nf] = __builtin_amdgcn_mfma_f32_16x16x32_bf16(a1, bf, acc[1][nf], 0,0,0);
        }
    }
    __syncthreads();                           // all Bs reads done; reuse as out-stage

    const float* bsrc = (nt < 2) ? b_in + nt*128
                     : (nt == 2) ? b_lam
                                 : b_gate + (nt-3)*128;
    #pragma unroll
    for (int nf = 0; nf < 8; ++nf) {
        int nl = nf*16 + lr;
        float bias = bsrc[nl];
        #pragma unroll
        for (int i = 0; i < 2; ++i)
        #pragma unroll
        for (int r = 0; r < 4; ++r) {
            int ml = wm + i*16 + rb + r;       // local row 0..127
            float v = acc[i][nf][r] + bias;
            float e = __expf(-v);
            float s = __builtin_amdgcn_rcpf(1.f + e);
            float outv = (nt == 2) ? e*s : v*s;
            *(u16*)(smem + ml*272 + nl*2) = f2b(outv);
        }
    }
    __syncthreads();

    #pragma unroll
    for (int it = 0; it < 8; ++it) {           // coalesced store: 2048 uint4
        int u = it*256 + tid;
        int row = u >> 4, c16 = u & 15;
        uint4 v = *(const uint4*)(smem + row*272 + c16*16);
        int m = m0 + row;
        if (nt < 2)
            *(uint4*)(&SC[(size_t)m*256 + nt*128 + c16*8]) = v;
        else if (nt == 2)
            *(uint4*)(&OM[(size_t)m*128 + c16*8]) = v;
        else
            *(uint4*)(&GATE[(size_t)m*256 + (nt-3)*128 + c16*8]) = v;
    }
}

// ---------------- K2: fused fwd+rev scans, 8-step batched loads --------------
// Per batch: issue 32 SC/OM loads + 16 P-RMW loads, then compute 8 steps
// register-only, then store 16 P words. Identical op sequence per chain as
// the serial version -> bit-exact. Batch F/R position ranges provably
// disjoint; cross-batch RMW ordering = same-thread program order.
template<int AXISW, int FIRSTPAIR>
__global__ __launch_bounds__(256) void k_scan2(const u16* __restrict__ SC,
                                               const u16* __restrict__ OM,
                                               const float* __restrict__ trig,
                                               u32* P)
{
    int j = blockIdx.x*256 + threadIdx.x;  // 131072 columns (full d)
    int d = j & 127;
    int col = j >> 7;                      // 0..1023
    int rowbase, stride;
    if (AXISW) { rowbase = (col>>3)*1024 + (col&7); stride = 8; }
    else       { rowbase = col;                     stride = 1024; }

    float cfF = trig[d],     sfF = trig[128+d];
    float cfR = trig[256+d], sfR = trig[384+d];

    long long rowF = rowbase;
    long long rowR = (long long)rowbase + (long long)stride*127;

    float hfr=0.f, hfi=0.f, hrr=0.f, hri=0.f;

    // One 8-step batch. RMW=0: store only (FIRSTPAIR first half).
    #define SCAN_BATCH(RMW)                                                   \
    {                                                                         \
        u32 uFv[8], uRv[8]; float omFv[8], omRv[8];                           \
        _Pragma("unroll")                                                     \
        for (int i = 0; i < 8; ++i) {                                         \
            long long rF = rowF + (long long)i*stride;                        \
            long long rR = rowR - (long long)i*stride;                        \
            uFv[i]  = *(const u32*)(SC + rF*256 + 2*d);                       \
            omFv[i] = b2f(OM[rF*128 + d]);                                    \
            uRv[i]  = *(const u32*)(SC + rR*256 + 2*d);                       \
            omRv[i] = b2f(OM[rR*128 + d]);                                    \
        }                                                                     \
        u32 pFo[8], pRo[8];                                                   \
        if (RMW) {                                                            \
            _Pragma("unroll")                                                 \
            for (int i = 0; i < 8; ++i) {                                     \
                pFo[i] = P[(rowF + (long long)i*stride)*128 + d];             \
                pRo[i] = P[(rowR - (long long)i*stride)*128 + d];             \
            }                                                                 \
        }                                                                     \
        u32 outFv[8], outRv[8];                                               \
        _Pragma("unroll")                                                     \
        for (int i = 0; i < 8; ++i) {                                         \
            float lamF = 1.f - omFv[i], lamR = 1.f - omRv[i];                 \
            float grF = lamF*cfF, giF = lamF*sfF;                             \
            float grR = lamR*cfR, giR = lamR*sfR;                             \
            float ieF = b2f((u16)(uFv[i] & 0xffff));                          \
            float ioF = b2f((u16)(uFv[i] >> 16));                             \
            float ieR = b2f((u16)(uRv[i] & 0xffff));                          \
            float ioR = b2f((u16)(uRv[i] >> 16));                             \
            float nfr = fmaf(grF, hfr, fmaf(-giF, hfi, omFv[i]*ieF));         \
            float nfi = fmaf(grF, hfi, fmaf( giF, hfr, omFv[i]*ioF));         \
            hfr = nfr; hfi = nfi;                                             \
            float nrr = fmaf(grR, hrr, fmaf(-giR, hri, omRv[i]*ieR));         \
            float nri = fmaf(grR, hri, fmaf( giR, hrr, omRv[i]*ioR));         \
            hrr = nrr; hri = nri;                                             \
            float oFr = hfr, oFi = hfi, oRr = hrr, oRi = hri;                 \
            if (RMW) {                                                        \
                oFr += b2f((u16)(pFo[i] & 0xffff));                           \
                oFi += b2f((u16)(pFo[i] >> 16));                              \
                oRr += b2f((u16)(pRo[i] & 0xffff));                           \
                oRi += b2f((u16)(pRo[i] >> 16));                              \
            }                                                                 \
            outFv[i] = pack2(oFr, oFi);                                       \
            outRv[i] = pack2(oRr, oRi);                                       \
        }                                                                     \
        _Pragma("unroll")                                                     \
        for (int i = 0; i < 8; ++i) {                                         \
            P[(rowF + (long long)i*stride)*128 + d] = outFv[i];               \
            P[(rowR - (long long)i*stride)*128 + d] = outRv[i];               \
        }                                                                     \
        rowF += 8*stride; rowR -= 8*stride;                                   \
    }

    if (FIRSTPAIR) {
        for (int tb = 0; tb < 8; ++tb) SCAN_BATCH(0)
        for (int tb = 0; tb < 8; ++tb) SCAN_BATCH(1)
    } else {
        for (int tb = 0; tb < 16; ++tb) SCAN_BATCH(1)
    }
    #undef SCAN_BATCH
}

// ---------------- K3: LN + gate + out GEMM via MFMA (r18-proven, staged B) --
#define GETC(v,i) ((i)==0?(v).x:(i)==1?(v).y:(i)==2?(v).z:(v).w)
__global__ __launch_bounds__(256) void k_backend_mfma(
    const uint4* __restrict__ P4, const u16* __restrict__ GATE,
    const u16* __restrict__ WoTn, const float* __restrict__ ln_w,
    const float* __restrict__ ln_b, const float* __restrict__ bo,
    float* __restrict__ out)
{
    __shared__ u16 fgM[64][264];                // 33.8 KiB bf16, [m][k], +8 pad
    __shared__ __align__(16) char wBs[16384];   // 16 KiB: B chunk [n][64k] swz
    int tid = threadIdx.x;
    int m0 = blockIdx.x * 64;                   // 2048 blocks
    int r = tid >> 2, q = tid & 3;              // 4 threads per row
    size_t prow4 = (size_t)(m0 + r)*32 + q*8;   // uint4 units (128 u32/row)
    size_t grow = (size_t)(m0 + r)*256;         // u16 units (GATE in ws)

    uint4 ga[4], gb[4];
    #pragma unroll
    for (int g4 = 0; g4 < 4; ++g4) {
        ga[g4] = *(const uint4*)(GATE + grow + q*32 + g4*8);
        gb[g4] = *(const uint4*)(GATE + grow + 128 + q*32 + g4*8);
    }

    uint4 pw[8];                                // 32 packed complex (bf16)
    #pragma unroll
    for (int c4 = 0; c4 < 8; ++c4) pw[c4] = P4[prow4 + c4];

    float fr_[32], fi_[32];
    #pragma unroll
    for (int c4 = 0; c4 < 8; ++c4) {
        #pragma unroll
        for (int w = 0; w < 4; ++w) {
            u32 word = GETC(pw[c4], w);
            int jj = c4*4 + w;
            fr_[jj] = b2f((u16)(word & 0xffff));
            fi_[jj] = b2f((u16)(word >> 16));
        }
    }

    float sum = 0.f, ss = 0.f;
    #pragma unroll
    for (int jj = 0; jj < 32; ++jj) {
        sum += fr_[jj] + fi_[jj];
        ss  += fr_[jj]*fr_[jj] + fi_[jj]*fi_[jj];
    }
    sum += __shfl_xor(sum, 1); sum += __shfl_xor(sum, 2);
    ss  += __shfl_xor(ss, 1);  ss  += __shfl_xor(ss, 2);
    float mu = sum * (1.f/256.f);
    float var = ss * (1.f/256.f) - mu*mu;
    float rstd = rsqrtf(var + 1e-5f);

    #pragma unroll
    for (int jj = 0; jj < 32; ++jj) {
        int pd = q*32 + jj;                     // complex channel 0..127
        int g4 = jj >> 3, e = jj & 7;
        u32 gur = GETC(ga[g4], e>>1), gui = GETC(gb[g4], e>>1);
        float gvr = b2f((u16)((e&1) ? (gur>>16) : (gur&0xffff)));
        float gvi = b2f((u16)((e&1) ? (gui>>16) : (gui&0xffff)));
        float vr = ((fr_[jj] - mu)*rstd*ln_w[pd]     + ln_b[pd])     * gvr;
        float vi = ((fi_[jj] - mu)*rstd*ln_w[128+pd] + ln_b[128+pd]) * gvi;
        fgM[r][pd]       = f2b(vr);
        fgM[r][128 + pd] = f2b(vi);
    }

    // out[64][128] = fgM @ WoTn^T via MFMA; wave w owns rows w*16..w*16+15
    int lane = tid & 63, w = tid >> 6;
    int lr = lane & 15, lk = (lane>>4)*8;
    int rb = (lane>>4)*4;

    frag_cd acc[8] = {};
    for (int kc = 0; kc < 4; ++kc) {
        __syncthreads();                        // fgM ready / prev wBs reads done
        #pragma unroll
        for (int it = 0; it < 4; ++it) {        // stage B chunk: 128n x 64k bf16
            int u = it*256 + tid;               // 1024 uint4 units
            int n = u >> 3, c8 = u & 7;
            int dst = (n<<7) + ((c8<<4) ^ ((n&7)<<4));
            *(uint4*)(wBs + dst) =
                *(const uint4*)(WoTn + (size_t)n*256 + kc*64 + c8*8);
        }
        __syncthreads();

        #pragma unroll
        for (int ks = 0; ks < 2; ++ks) {
            int kglob = kc*64 + ks*32 + lk;
            frag_ab a = *(const frag_ab*)(&fgM[w*16 + lr][kglob]);
            int kb2 = (ks*32 + lk)*2;           // byte offset in 128B row
            #pragma unroll
            for (int nf = 0; nf < 8; ++nf) {
                int rn = nf*16 + lr;
                frag_ab b = *(const frag_ab*)(wBs + (rn<<7) + (kb2 ^ ((rn&7)<<4)));
                acc[nf] = __builtin_amdgcn_mfma_f32_16x16x32_bf16(a, b, acc[nf], 0,0,0);
            }
        }
    }

    #pragma unroll
    for (int nf = 0; nf < 8; ++nf) {
        int n = nf*16 + lr;
        float bias = bo[n];
        #pragma unroll
        for (int rr = 0; rr < 4; ++rr) {
            int m = m0 + w*16 + rb + rr;
            out[(size_t)m*128 + n] = acc[nf][rr] + bias;
        }
    }
}

// ---------------- launch -----------------------------------------------------
extern "C" void kernel_launch(void* const* d_in, const int* in_sizes, int n_in,
                              void* d_out, int out_size, void* d_ws, size_t ws_size,
                              hipStream_t stream)
{
    const float* x      = (const float*)d_in[0];
    const float* W_in   = (const float*)d_in[1];
    const float* b_in   = (const float*)d_in[2];
    const float* W_lam  = (const float*)d_in[3];
    const float* b_lam  = (const float*)d_in[4];
    const float* th_f   = (const float*)d_in[5];
    const float* th_r   = (const float*)d_in[6];
    const float* W_gate = (const float*)d_in[7];
    const float* b_gate = (const float*)d_in[8];
    const float* W_out  = (const float*)d_in[9];
    const float* b_out  = (const float*)d_in[10];
    const float* ln_w   = (const float*)d_in[11];
    const float* ln_b   = (const float*)d_in[12];

    // ws layout: 168,003,584 B <= 168,008,192 B proven-safe envelope
    char* ws = (char*)d_ws;
    u32* P     = (u32*)(ws);                      //  67,108,864 (bf16-pair, full d)
    u16* xb    = (u16*)(ws);                      //  33,554,432 ALIASES P (disjoint
                                                  //  lifetime: xb dies at front end;
                                                  //  P first written by scan1)
    u16* OM    = (u16*)(ws + 67108864LL);         //  33,554,432 (bf16 om, full d)
    u16* GATE  = (u16*)(ws + 100663296LL);        //  67,108,864 (bf16 gate)
    float* trig= (float*)(ws + 167772160LL);      //   2,048
    u16* WoTn  = (u16*)(ws + 167774208LL);        //  65,536 (bf16 W_out, n-major)
    u16* WtB   = (u16*)(ws + 167839744LL);        // 163,840 (bf16 front W, n-major)

    // d_out time-shares: SC bf16[M][256] (front->scans) -> out f32[M][128]
    u16* SC   = (u16*)d_out;
    float* out = (float*)d_out;

    hipLaunchKernelGGL(k_prep, dim3(897), dim3(128), 0, stream,
                       th_f, th_r, W_in, W_lam, W_gate, W_out, trig, WoTn, WtB);
    hipLaunchKernelGGL(k_cast, dim3(8192), dim3(256), 0, stream,
                       (const float4*)x, (uint4*)xb);

    hipLaunchKernelGGL(k_front_mfma, dim3(5120), dim3(256), 0, stream,
                       xb, WtB, b_in, b_lam, b_gate, SC, OM, GATE);

    hipLaunchKernelGGL(HIP_KERNEL_NAME(k_scan2<0,1>), dim3(512), dim3(256), 0, stream,
                       SC, OM, trig, P);
    hipLaunchKernelGGL(HIP_KERNEL_NAME(k_scan2<1,0>), dim3(512), dim3(256), 0, stream,
                       SC, OM, trig, P);

    hipLaunchKernelGGL(k_backend_mfma, dim3(2048), dim3(256), 0, stream,
                       (const uint4*)P, GATE, WoTn, ln_w, ln_b, b_out, out);
}